// Round 1
// baseline (368.210 us; speedup 1.0000x reference)
//
#include <hip/hip_runtime.h>
#include <hip/hip_bf16.h>
#include <math.h>

#define HIDDEN 1024
#define HEADS 16
#define DK 64
#define BB 2
#define SS 2048
#define MROWS (BB*SS)  /* 4096 */

typedef __attribute__((ext_vector_type(8))) short short8;
typedef __attribute__((ext_vector_type(4))) float f32x4;
typedef __attribute__((ext_vector_type(4))) unsigned short ushort4_t;

static __device__ __forceinline__ unsigned short f2bf(float f) {
    // round-to-nearest-even fp32 -> bf16 (inputs are finite)
    unsigned int u = __float_as_uint(f);
    u += 0x7fffu + ((u >> 16) & 1u);
    return (unsigned short)(u >> 16);
}
static __device__ __forceinline__ float bf2f(unsigned short s) {
    return __uint_as_float(((unsigned int)s) << 16);
}

// ---------------------------------------------------------------- cast fp32 -> bf16
__global__ void cast_f32_bf16(const float* __restrict__ in, unsigned short* __restrict__ out, int n4) {
    int i = blockIdx.x * blockDim.x + threadIdx.x;
    if (i < n4) {
        float4 v = reinterpret_cast<const float4*>(in)[i];
        ushort4_t o;
        o.x = f2bf(v.x); o.y = f2bf(v.y); o.z = f2bf(v.z); o.w = f2bf(v.w);
        reinterpret_cast<ushort4_t*>(out)[i] = o;
    }
}

// ---------------------------------------------------------------- GEMM: out = A[M,K] * W[N,K]^T + bias
// MODE 0: out bf16, scatter to [B,H,S,D]   (Q, K projections)
// MODE 1: out bf16, scatter to [B,H,D,S]   (V projection, pre-transposed)
// MODE 2: out fp32, [M,N] row-major        (final output projection)
template<int MODE>
__global__ __launch_bounds__(256) void gemm_bt(const unsigned short* __restrict__ A,
                                               const unsigned short* __restrict__ Wt,
                                               const float* __restrict__ bias,
                                               void* __restrict__ outp,
                                               int M, int N, int K) {
    __shared__ unsigned short As[128][40];  // +8 pad: 80B row stride, conflict-light
    __shared__ unsigned short Bs[128][40];
    const int t    = threadIdx.x;
    const int lane = t & 63;
    const int wave = t >> 6;
    const int m0 = blockIdx.y * 128;
    const int n0 = blockIdx.x * 128;
    const int row  = t >> 2;        // 0..63
    const int col8 = (t & 3) * 8;   // 0,8,16,24

    const int wm = (wave >> 1) * 64;
    const int wn = (wave & 1) * 64;
    const int lr = lane & 15;
    const int lk = (lane >> 4) * 8;

    f32x4 acc[4][4];
#pragma unroll
    for (int i = 0; i < 4; i++)
#pragma unroll
        for (int j = 0; j < 4; j++) acc[i][j] = f32x4{0.f, 0.f, 0.f, 0.f};

    for (int k0 = 0; k0 < K; k0 += 32) {
        short8 av0 = *reinterpret_cast<const short8*>(A  + (size_t)(m0 + row)      * K + k0 + col8);
        short8 av1 = *reinterpret_cast<const short8*>(A  + (size_t)(m0 + row + 64) * K + k0 + col8);
        short8 bv0 = *reinterpret_cast<const short8*>(Wt + (size_t)(n0 + row)      * K + k0 + col8);
        short8 bv1 = *reinterpret_cast<const short8*>(Wt + (size_t)(n0 + row + 64) * K + k0 + col8);
        __syncthreads();  // previous iteration's LDS reads complete
        *reinterpret_cast<short8*>(&As[row][col8])      = av0;
        *reinterpret_cast<short8*>(&As[row + 64][col8]) = av1;
        *reinterpret_cast<short8*>(&Bs[row][col8])      = bv0;
        *reinterpret_cast<short8*>(&Bs[row + 64][col8]) = bv1;
        __syncthreads();
        short8 af[4], bfr[4];
#pragma unroll
        for (int i = 0; i < 4; i++) af[i]  = *reinterpret_cast<const short8*>(&As[wm + i * 16 + lr][lk]);
#pragma unroll
        for (int j = 0; j < 4; j++) bfr[j] = *reinterpret_cast<const short8*>(&Bs[wn + j * 16 + lr][lk]);
#pragma unroll
        for (int i = 0; i < 4; i++)
#pragma unroll
            for (int j = 0; j < 4; j++)
                acc[i][j] = __builtin_amdgcn_mfma_f32_16x16x32_bf16(af[i], bfr[j], acc[i][j], 0, 0, 0);
    }

    // epilogue: C/D layout col = lane&15, row = (lane>>4)*4 + reg   [m89-verified]
#pragma unroll
    for (int i = 0; i < 4; i++) {
        int mrow = m0 + wm + i * 16 + (lane >> 4) * 4;
#pragma unroll
        for (int j = 0; j < 4; j++) {
            int ncol = n0 + wn + j * 16 + lr;
            float bv = bias[ncol];
            if (MODE == 2) {
                float* O = (float*)outp;
#pragma unroll
                for (int r = 0; r < 4; r++)
                    O[(size_t)(mrow + r) * N + ncol] = acc[i][j][r] + bv;
            } else {
                unsigned short* O = (unsigned short*)outp;
                int b_ = mrow >> 11;      // S=2048
                int h_ = ncol >> 6;
                int d_ = ncol & 63;
                if (MODE == 0) {
#pragma unroll
                    for (int r = 0; r < 4; r++) {
                        int s_ = (mrow + r) & 2047;
                        O[(((size_t)(b_ * HEADS + h_)) * SS + s_) * DK + d_] = f2bf(acc[i][j][r] + bv);
                    }
                } else {  // MODE 1: Vt[b,h,d,s]; 4 regs are consecutive s -> packed 8B store
                    int s0 = mrow & 2047;
                    ushort4_t pk;
                    pk.x = f2bf(acc[i][j][0] + bv);
                    pk.y = f2bf(acc[i][j][1] + bv);
                    pk.z = f2bf(acc[i][j][2] + bv);
                    pk.w = f2bf(acc[i][j][3] + bv);
                    *reinterpret_cast<ushort4_t*>(O + (((size_t)(b_ * HEADS + h_) * DK + d_) * SS + s0)) = pk;
                }
            }
        }
    }
}

// ---------------------------------------------------------------- flash attention
// Q,K: [B,H,S,D] bf16;  Vt: [B,H,D,S] bf16;  Y: [B,S,HIDDEN] bf16
// 4 independent waves per block, 16 q-rows per wave, KV blocks of 32. No barriers.
__global__ __launch_bounds__(256) void attn_kernel(const unsigned short* __restrict__ Qb,
                                                   const unsigned short* __restrict__ Kb,
                                                   const unsigned short* __restrict__ Vt,
                                                   unsigned short* __restrict__ Yb) {
    __shared__ unsigned short Pl[4][16][40];  // per-wave P tile (16q x 32kv, padded)
    const int t    = threadIdx.x;
    const int lane = t & 63;
    const int wave = t >> 6;
    const int bh = blockIdx.y;
    const int b_ = bh >> 4, h_ = bh & 15;
    const int qbase = blockIdx.x * 64 + wave * 16;
    const unsigned short* Qp = Qb + (size_t)bh * SS * DK;
    const unsigned short* Kp = Kb + (size_t)bh * SS * DK;
    const unsigned short* Vp = Vt + (size_t)bh * DK * SS;
    const int lr = lane & 15;
    const int lk = (lane >> 4) * 8;

    // Q A-frags hoisted (d 0..31, 32..63)
    short8 aq0 = *reinterpret_cast<const short8*>(Qp + (size_t)(qbase + lr) * DK + lk);
    short8 aq1 = *reinterpret_cast<const short8*>(Qp + (size_t)(qbase + lr) * DK + 32 + lk);

    f32x4 accd[4];
#pragma unroll
    for (int d = 0; d < 4; d++) accd[d] = f32x4{0.f, 0.f, 0.f, 0.f};
    float mi[4] = {-INFINITY, -INFINITY, -INFINITY, -INFINITY};
    float li[4] = {0.f, 0.f, 0.f, 0.f};

    for (int kvb = 0; kvb < SS; kvb += 32) {
        short8 bk00 = *reinterpret_cast<const short8*>(Kp + (size_t)(kvb + lr) * DK + lk);
        short8 bk01 = *reinterpret_cast<const short8*>(Kp + (size_t)(kvb + lr) * DK + 32 + lk);
        short8 bk10 = *reinterpret_cast<const short8*>(Kp + (size_t)(kvb + 16 + lr) * DK + lk);
        short8 bk11 = *reinterpret_cast<const short8*>(Kp + (size_t)(kvb + 16 + lr) * DK + 32 + lk);
        f32x4 s0 = f32x4{0.f, 0.f, 0.f, 0.f};
        f32x4 s1 = f32x4{0.f, 0.f, 0.f, 0.f};
        s0 = __builtin_amdgcn_mfma_f32_16x16x32_bf16(aq0, bk00, s0, 0, 0, 0);
        s0 = __builtin_amdgcn_mfma_f32_16x16x32_bf16(aq1, bk01, s0, 0, 0, 0);
        s1 = __builtin_amdgcn_mfma_f32_16x16x32_bf16(aq0, bk10, s1, 0, 0, 0);
        s1 = __builtin_amdgcn_mfma_f32_16x16x32_bf16(aq1, bk11, s1, 0, 0, 0);

        float mnew[4], sc[4];
#pragma unroll
        for (int r = 0; r < 4; r++) {
            s0[r] *= 0.125f;
            s1[r] *= 0.125f;
            float v = fmaxf(s0[r], s1[r]);
            v = fmaxf(v, __shfl_xor(v, 1));
            v = fmaxf(v, __shfl_xor(v, 2));
            v = fmaxf(v, __shfl_xor(v, 4));
            v = fmaxf(v, __shfl_xor(v, 8));
            mnew[r] = fmaxf(mi[r], v);
            sc[r] = __expf(mi[r] - mnew[r]);   // exp(-inf)=0 on first tile
            mi[r] = mnew[r];
            li[r] *= sc[r];
        }
#pragma unroll
        for (int r = 0; r < 4; r++) {
            float p0 = __expf(s0[r] - mnew[r]);
            float p1 = __expf(s1[r] - mnew[r]);
            float rs = p0 + p1;
            rs += __shfl_xor(rs, 1);
            rs += __shfl_xor(rs, 2);
            rs += __shfl_xor(rs, 4);
            rs += __shfl_xor(rs, 8);
            li[r] += rs;
            int q = (lane >> 4) * 4 + r;
            Pl[wave][q][lr]      = f2bf(p0);
            Pl[wave][q][16 + lr] = f2bf(p1);
        }
#pragma unroll
        for (int d = 0; d < 4; d++) {
#pragma unroll
            for (int r = 0; r < 4; r++) accd[d][r] *= sc[r];
        }
        short8 ap = *reinterpret_cast<const short8*>(&Pl[wave][lr][lk]);
#pragma unroll
        for (int d = 0; d < 4; d++) {
            short8 bv = *reinterpret_cast<const short8*>(Vp + (size_t)(d * 16 + lr) * SS + kvb + lk);
            accd[d] = __builtin_amdgcn_mfma_f32_16x16x32_bf16(ap, bv, accd[d], 0, 0, 0);
        }
    }

    float inv[4];
#pragma unroll
    for (int r = 0; r < 4; r++) inv[r] = 1.f / li[r];
    size_t outbase = (size_t)b_ * SS * HIDDEN + (size_t)h_ * DK;
#pragma unroll
    for (int d = 0; d < 4; d++) {
#pragma unroll
        for (int r = 0; r < 4; r++) {
            int q = qbase + (lane >> 4) * 4 + r;
            Yb[outbase + (size_t)q * HIDDEN + d * 16 + lr] = f2bf(accd[d][r] * inv[r]);
        }
    }
}

// ---------------------------------------------------------------- launch
extern "C" void kernel_launch(void* const* d_in, const int* in_sizes, int n_in,
                              void* d_out, int out_size, void* d_ws, size_t ws_size,
                              hipStream_t stream) {
    const float* query = (const float*)d_in[0];
    const float* key_  = (const float*)d_in[1];
    const float* value = (const float*)d_in[2];
    const float* w_q = (const float*)d_in[3];
    const float* b_q = (const float*)d_in[4];
    const float* w_k = (const float*)d_in[5];
    const float* b_k = (const float*)d_in[6];
    const float* w_v = (const float*)d_in[7];
    const float* b_v = (const float*)d_in[8];
    const float* w_o = (const float*)d_in[9];
    const float* b_o = (const float*)d_in[10];

    const size_t SZ_X = (size_t)MROWS * HIDDEN * 2;   // 8 MiB
    const size_t SZ_W = (size_t)HIDDEN * HIDDEN * 2;  // 2 MiB
    char* ws = (char*)d_ws;
    unsigned short* Xq = (unsigned short*)(ws);
    unsigned short* Xk = (unsigned short*)(ws + SZ_X);
    unsigned short* Xv = (unsigned short*)(ws + 2 * SZ_X);
    unsigned short* Wq = (unsigned short*)(ws + 3 * SZ_X);
    unsigned short* Wk = (unsigned short*)(ws + 3 * SZ_X + SZ_W);
    unsigned short* Wv = (unsigned short*)(ws + 3 * SZ_X + 2 * SZ_W);
    unsigned short* Wo = (unsigned short*)(ws + 3 * SZ_X + 3 * SZ_W);
    unsigned short* Qb = (unsigned short*)(ws + 3 * SZ_X + 4 * SZ_W);
    unsigned short* Kb = (unsigned short*)(ws + 4 * SZ_X + 4 * SZ_W);
    unsigned short* Vt = (unsigned short*)(ws + 5 * SZ_X + 4 * SZ_W);
    unsigned short* Yb = (unsigned short*)(ws + 6 * SZ_X + 4 * SZ_W);
    float* out = (float*)d_out;

    const int n4x = MROWS * HIDDEN / 4;    // 1,048,576
    const int n4w = HIDDEN * HIDDEN / 4;   // 262,144
    cast_f32_bf16<<<n4x / 256, 256, 0, stream>>>(query, Xq, n4x);
    cast_f32_bf16<<<n4x / 256, 256, 0, stream>>>(key_,  Xk, n4x);
    cast_f32_bf16<<<n4x / 256, 256, 0, stream>>>(value, Xv, n4x);
    cast_f32_bf16<<<n4w / 256, 256, 0, stream>>>(w_q, Wq, n4w);
    cast_f32_bf16<<<n4w / 256, 256, 0, stream>>>(w_k, Wk, n4w);
    cast_f32_bf16<<<n4w / 256, 256, 0, stream>>>(w_v, Wv, n4w);
    cast_f32_bf16<<<n4w / 256, 256, 0, stream>>>(w_o, Wo, n4w);

    dim3 gg(HIDDEN / 128, MROWS / 128);  // (8, 32)
    gemm_bt<0><<<gg, 256, 0, stream>>>(Xq, Wq, b_q, (void*)Qb, MROWS, HIDDEN, HIDDEN);
    gemm_bt<0><<<gg, 256, 0, stream>>>(Xk, Wk, b_k, (void*)Kb, MROWS, HIDDEN, HIDDEN);
    gemm_bt<1><<<gg, 256, 0, stream>>>(Xv, Wv, b_v, (void*)Vt, MROWS, HIDDEN, HIDDEN);

    attn_kernel<<<dim3(SS / 64, BB * HEADS), 256, 0, stream>>>(Qb, Kb, Vt, Yb);

    gemm_bt<2><<<gg, 256, 0, stream>>>(Yb, Wo, b_o, d_out, MROWS, HIDDEN, HIDDEN);
}

// Round 2
// 353.897 us; speedup vs baseline: 1.0404x; 1.0404x over previous
//
#include <hip/hip_runtime.h>
#include <hip/hip_bf16.h>
#include <math.h>

#define HIDDEN 1024
#define HEADS 16
#define DK 64
#define BB 2
#define SS 2048
#define MROWS (BB*SS)  /* 4096 */

typedef __attribute__((ext_vector_type(8))) short short8;
typedef __attribute__((ext_vector_type(4))) float f32x4;
typedef __attribute__((ext_vector_type(4))) unsigned short ushort4_t;

static __device__ __forceinline__ unsigned short f2bf(float f) {
    unsigned int u = __float_as_uint(f);
    u += 0x7fffu + ((u >> 16) & 1u);
    return (unsigned short)(u >> 16);
}

// ---------------------------------------------------------------- fused cast fp32 -> bf16 (all 7 tensors)
__global__ __launch_bounds__(256) void cast_all(
    const float* __restrict__ q, const float* __restrict__ k, const float* __restrict__ v,
    const float* __restrict__ wq, const float* __restrict__ wk,
    const float* __restrict__ wv, const float* __restrict__ wo,
    unsigned short* __restrict__ Xq, unsigned short* __restrict__ Xk, unsigned short* __restrict__ Xv,
    unsigned short* __restrict__ Wq, unsigned short* __restrict__ Wk,
    unsigned short* __restrict__ Wv, unsigned short* __restrict__ Wo) {
    int i = blockIdx.x * 256 + threadIdx.x;   // float4 index
    const float* src; unsigned short* dst; int off;
    if (i < (3 << 20)) {                      // X tensors: 2^20 float4 each
        int w = i >> 20; off = i & ((1 << 20) - 1);
        src = (w == 0) ? q : (w == 1) ? k : v;
        dst = (w == 0) ? Xq : (w == 1) ? Xk : Xv;
    } else {                                  // W tensors: 2^18 float4 each
        int j = i - (3 << 20);
        int w = j >> 18; off = j & ((1 << 18) - 1);
        src = (w == 0) ? wq : (w == 1) ? wk : (w == 2) ? wv : wo;
        dst = (w == 0) ? Wq : (w == 1) ? Wk : (w == 2) ? Wv : Wo;
    }
    float4 f = reinterpret_cast<const float4*>(src)[off];
    ushort4_t o;
    o.x = f2bf(f.x); o.y = f2bf(f.y); o.z = f2bf(f.z); o.w = f2bf(f.w);
    reinterpret_cast<ushort4_t*>(dst)[off] = o;
}

// ---------------------------------------------------------------- GEMM: out = (A[M,K] * W[N,K]^T + bias) * oscale
// MODE 0: out bf16, scatter to [B,H,S,D]   (Q, K projections)
// MODE 1: out bf16, scatter to [B,H,D,S]   (V projection, pre-transposed)
// MODE 2: out fp32, [M,N] row-major        (final output projection; oscale ignored)
template<int MODE>
__global__ __launch_bounds__(256) void gemm_bt(const unsigned short* __restrict__ A,
                                               const unsigned short* __restrict__ Wt,
                                               const float* __restrict__ bias,
                                               void* __restrict__ outp,
                                               int M, int N, int K, float oscale) {
    __shared__ unsigned short As[128][40];
    __shared__ unsigned short Bs[128][40];
    const int t    = threadIdx.x;
    const int lane = t & 63;
    const int wave = t >> 6;
    const int m0 = blockIdx.y * 128;
    const int n0 = blockIdx.x * 128;
    const int row  = t >> 2;
    const int col8 = (t & 3) * 8;

    const int wm = (wave >> 1) * 64;
    const int wn = (wave & 1) * 64;
    const int lr = lane & 15;
    const int lk = (lane >> 4) * 8;

    f32x4 acc[4][4];
#pragma unroll
    for (int i = 0; i < 4; i++)
#pragma unroll
        for (int j = 0; j < 4; j++) acc[i][j] = f32x4{0.f, 0.f, 0.f, 0.f};

    for (int k0 = 0; k0 < K; k0 += 32) {
        short8 av0 = *reinterpret_cast<const short8*>(A  + (size_t)(m0 + row)      * K + k0 + col8);
        short8 av1 = *reinterpret_cast<const short8*>(A  + (size_t)(m0 + row + 64) * K + k0 + col8);
        short8 bv0 = *reinterpret_cast<const short8*>(Wt + (size_t)(n0 + row)      * K + k0 + col8);
        short8 bv1 = *reinterpret_cast<const short8*>(Wt + (size_t)(n0 + row + 64) * K + k0 + col8);
        __syncthreads();
        *reinterpret_cast<short8*>(&As[row][col8])      = av0;
        *reinterpret_cast<short8*>(&As[row + 64][col8]) = av1;
        *reinterpret_cast<short8*>(&Bs[row][col8])      = bv0;
        *reinterpret_cast<short8*>(&Bs[row + 64][col8]) = bv1;
        __syncthreads();
        short8 af[4], bfr[4];
#pragma unroll
        for (int i = 0; i < 4; i++) af[i]  = *reinterpret_cast<const short8*>(&As[wm + i * 16 + lr][lk]);
#pragma unroll
        for (int j = 0; j < 4; j++) bfr[j] = *reinterpret_cast<const short8*>(&Bs[wn + j * 16 + lr][lk]);
#pragma unroll
        for (int i = 0; i < 4; i++)
#pragma unroll
            for (int j = 0; j < 4; j++)
                acc[i][j] = __builtin_amdgcn_mfma_f32_16x16x32_bf16(af[i], bfr[j], acc[i][j], 0, 0, 0);
    }

#pragma unroll
    for (int i = 0; i < 4; i++) {
        int mrow = m0 + wm + i * 16 + (lane >> 4) * 4;
#pragma unroll
        for (int j = 0; j < 4; j++) {
            int ncol = n0 + wn + j * 16 + lr;
            float bv = bias[ncol];
            if (MODE == 2) {
                float* O = (float*)outp;
#pragma unroll
                for (int r = 0; r < 4; r++)
                    O[(size_t)(mrow + r) * N + ncol] = acc[i][j][r] + bv;
            } else {
                unsigned short* O = (unsigned short*)outp;
                int b_ = mrow >> 11;
                int h_ = ncol >> 6;
                int d_ = ncol & 63;
                if (MODE == 0) {
#pragma unroll
                    for (int r = 0; r < 4; r++) {
                        int s_ = (mrow + r) & 2047;
                        O[(((size_t)(b_ * HEADS + h_)) * SS + s_) * DK + d_] = f2bf((acc[i][j][r] + bv) * oscale);
                    }
                } else {
                    int s0 = mrow & 2047;
                    ushort4_t pk;
                    pk.x = f2bf((acc[i][j][0] + bv) * oscale);
                    pk.y = f2bf((acc[i][j][1] + bv) * oscale);
                    pk.z = f2bf((acc[i][j][2] + bv) * oscale);
                    pk.w = f2bf((acc[i][j][3] + bv) * oscale);
                    *reinterpret_cast<ushort4_t*>(O + (((size_t)(b_ * HEADS + h_) * DK + d_) * SS + s0)) = pk;
                }
            }
        }
    }
}

// ---------------------------------------------------------------- flash attention v2 (swapped operands)
// Q:[B,H,S,D] bf16 PRE-SCALED by 0.125*log2e;  K:[B,H,S,D];  Vt:[B,H,D,S];  Y:[B,S,HIDDEN] bf16
// 4 independent waves/block, 16 q-rows/wave, KV step 32, K reg-double-buffered, V loaded early.
// Swapped QK^T: s[t] = mfma(Kfrag, Qfrag) -> S^T[kv][q]: lane holds 8 kv scores for q=lane&15.
// Swapped PV:   accd[dt] = mfma(Vtfrag, Pfrag) -> O^T[d][q]: col=lane&15=q, so m/l stay lane-local.
__global__ __launch_bounds__(256) void attn_kernel(const unsigned short* __restrict__ Qb,
                                                   const unsigned short* __restrict__ Kb,
                                                   const unsigned short* __restrict__ Vt,
                                                   unsigned short* __restrict__ Yb) {
    __shared__ unsigned short Pl[4][16][40];
    const int t    = threadIdx.x;
    const int lane = t & 63;
    const int wave = t >> 6;
    const int bh = blockIdx.y;
    const int b_ = bh >> 4, h_ = bh & 15;
    const int qbase = blockIdx.x * 64 + wave * 16;
    const unsigned short* Qp = Qb + (size_t)bh * SS * DK;
    const unsigned short* Kp = Kb + (size_t)bh * SS * DK;
    const unsigned short* Vp = Vt + (size_t)bh * DK * SS;
    const int lr = lane & 15;
    const int g  = lane >> 4;
    const int lk = g * 8;

    const unsigned short* Kbase = Kp + (size_t)lr * DK + lk;
    const unsigned short* Vbase = Vp + (size_t)lr * SS + lk;

    // Q B-frags (already scaled by 0.125*log2e)
    short8 bq0 = *reinterpret_cast<const short8*>(Qp + (size_t)(qbase + lr) * DK + lk);
    short8 bq1 = *reinterpret_cast<const short8*>(Qp + (size_t)(qbase + lr) * DK + 32 + lk);

    f32x4 accd[4];
#pragma unroll
    for (int d = 0; d < 4; d++) accd[d] = f32x4{0.f, 0.f, 0.f, 0.f};
    float mi = -INFINITY, li = 0.f;

    short8 kA0, kA1, kA2, kA3, kB0, kB1, kB2, kB3, vv0, vv1, vv2, vv3;

#define LOADK(D0, D1, D2, D3, KVB) do {                                          \
    D0 = *reinterpret_cast<const short8*>(Kbase + (size_t)(KVB) * DK);           \
    D1 = *reinterpret_cast<const short8*>(Kbase + (size_t)(KVB) * DK + 32);      \
    D2 = *reinterpret_cast<const short8*>(Kbase + (size_t)(KVB) * DK + 16 * DK); \
    D3 = *reinterpret_cast<const short8*>(Kbase + (size_t)(KVB) * DK + 16 * DK + 32); \
} while (0)

#define LOADV(KVB) do {                                                  \
    vv0 = *reinterpret_cast<const short8*>(Vbase + (KVB));               \
    vv1 = *reinterpret_cast<const short8*>(Vbase + 16 * SS + (KVB));     \
    vv2 = *reinterpret_cast<const short8*>(Vbase + 32 * SS + (KVB));     \
    vv3 = *reinterpret_cast<const short8*>(Vbase + 48 * SS + (KVB));     \
} while (0)

#define ATTN_STEP(K0, K1, K2, K3) do {                                                  \
    f32x4 s0 = f32x4{0.f,0.f,0.f,0.f}, s1 = f32x4{0.f,0.f,0.f,0.f};                     \
    s0 = __builtin_amdgcn_mfma_f32_16x16x32_bf16(K0, bq0, s0, 0, 0, 0);                 \
    s0 = __builtin_amdgcn_mfma_f32_16x16x32_bf16(K1, bq1, s0, 0, 0, 0);                 \
    s1 = __builtin_amdgcn_mfma_f32_16x16x32_bf16(K2, bq0, s1, 0, 0, 0);                 \
    s1 = __builtin_amdgcn_mfma_f32_16x16x32_bf16(K3, bq1, s1, 0, 0, 0);                 \
    float vmax = fmaxf(fmaxf(fmaxf(s0[0], s0[1]), fmaxf(s0[2], s0[3])),                 \
                       fmaxf(fmaxf(s1[0], s1[1]), fmaxf(s1[2], s1[3])));                \
    vmax = fmaxf(vmax, __shfl_xor(vmax, 16));                                           \
    vmax = fmaxf(vmax, __shfl_xor(vmax, 32));                                           \
    if (!__all(vmax <= mi + 8.0f)) {                                                    \
        float mnew = fmaxf(mi, vmax);                                                   \
        float sc = __builtin_amdgcn_exp2f(mi - mnew);                                   \
        li *= sc;                                                                       \
        for (int _d = 0; _d < 4; _d++)                                                  \
            for (int _r = 0; _r < 4; _r++) accd[_d][_r] *= sc;                          \
        mi = mnew;                                                                      \
    }                                                                                   \
    float p0 = __builtin_amdgcn_exp2f(s0[0] - mi), p1 = __builtin_amdgcn_exp2f(s0[1] - mi); \
    float p2 = __builtin_amdgcn_exp2f(s0[2] - mi), p3 = __builtin_amdgcn_exp2f(s0[3] - mi); \
    float p4 = __builtin_amdgcn_exp2f(s1[0] - mi), p5 = __builtin_amdgcn_exp2f(s1[1] - mi); \
    float p6 = __builtin_amdgcn_exp2f(s1[2] - mi), p7 = __builtin_amdgcn_exp2f(s1[3] - mi); \
    float rs = ((p0 + p1) + (p2 + p3)) + ((p4 + p5) + (p6 + p7));                       \
    rs += __shfl_xor(rs, 16);                                                           \
    rs += __shfl_xor(rs, 32);                                                           \
    li += rs;                                                                           \
    ushort4_t pk0; pk0.x = f2bf(p0); pk0.y = f2bf(p1); pk0.z = f2bf(p2); pk0.w = f2bf(p3); \
    ushort4_t pk1; pk1.x = f2bf(p4); pk1.y = f2bf(p5); pk1.z = f2bf(p6); pk1.w = f2bf(p7); \
    *reinterpret_cast<ushort4_t*>(&Pl[wave][lr][g * 4])      = pk0;                     \
    *reinterpret_cast<ushort4_t*>(&Pl[wave][lr][16 + g * 4]) = pk1;                     \
    short8 pf = *reinterpret_cast<const short8*>(&Pl[wave][lr][g * 8]);                 \
    accd[0] = __builtin_amdgcn_mfma_f32_16x16x32_bf16(vv0, pf, accd[0], 0, 0, 0);       \
    accd[1] = __builtin_amdgcn_mfma_f32_16x16x32_bf16(vv1, pf, accd[1], 0, 0, 0);       \
    accd[2] = __builtin_amdgcn_mfma_f32_16x16x32_bf16(vv2, pf, accd[2], 0, 0, 0);       \
    accd[3] = __builtin_amdgcn_mfma_f32_16x16x32_bf16(vv3, pf, accd[3], 0, 0, 0);       \
} while (0)

    LOADK(kA0, kA1, kA2, kA3, 0);
    for (int kvb = 0; kvb < SS; kvb += 64) {
        LOADV(kvb);                              // V for step A (consumed after softmax)
        LOADK(kB0, kB1, kB2, kB3, kvb + 32);     // K for step B (one step ahead)
        ATTN_STEP(kA0, kA1, kA2, kA3);
        LOADV(kvb + 32);                         // V for step B
        if (kvb + 64 < SS) LOADK(kA0, kA1, kA2, kA3, kvb + 64);  // K for next iter's step A
        ATTN_STEP(kB0, kB1, kB2, kB3);
    }
#undef LOADK
#undef LOADV
#undef ATTN_STEP

    float inv = 1.0f / li;
    size_t ob = (size_t)b_ * SS * HIDDEN + (size_t)(qbase + lr) * HIDDEN + (size_t)h_ * DK + g * 4;
#pragma unroll
    for (int dt = 0; dt < 4; dt++) {
        ushort4_t o;
        o.x = f2bf(accd[dt][0] * inv);
        o.y = f2bf(accd[dt][1] * inv);
        o.z = f2bf(accd[dt][2] * inv);
        o.w = f2bf(accd[dt][3] * inv);
        *reinterpret_cast<ushort4_t*>(Yb + ob + dt * 16) = o;
    }
}

// ---------------------------------------------------------------- launch
extern "C" void kernel_launch(void* const* d_in, const int* in_sizes, int n_in,
                              void* d_out, int out_size, void* d_ws, size_t ws_size,
                              hipStream_t stream) {
    const float* query = (const float*)d_in[0];
    const float* key_  = (const float*)d_in[1];
    const float* value = (const float*)d_in[2];
    const float* w_q = (const float*)d_in[3];
    const float* b_q = (const float*)d_in[4];
    const float* w_k = (const float*)d_in[5];
    const float* b_k = (const float*)d_in[6];
    const float* w_v = (const float*)d_in[7];
    const float* b_v = (const float*)d_in[8];
    const float* w_o = (const float*)d_in[9];
    const float* b_o = (const float*)d_in[10];

    const size_t SZ_X = (size_t)MROWS * HIDDEN * 2;
    const size_t SZ_W = (size_t)HIDDEN * HIDDEN * 2;
    char* ws = (char*)d_ws;
    unsigned short* Xq = (unsigned short*)(ws);
    unsigned short* Xk = (unsigned short*)(ws + SZ_X);
    unsigned short* Xv = (unsigned short*)(ws + 2 * SZ_X);
    unsigned short* Wq = (unsigned short*)(ws + 3 * SZ_X);
    unsigned short* Wk = (unsigned short*)(ws + 3 * SZ_X + SZ_W);
    unsigned short* Wv = (unsigned short*)(ws + 3 * SZ_X + 2 * SZ_W);
    unsigned short* Wo = (unsigned short*)(ws + 3 * SZ_X + 3 * SZ_W);
    unsigned short* Qb = (unsigned short*)(ws + 3 * SZ_X + 4 * SZ_W);
    unsigned short* Kbf = (unsigned short*)(ws + 4 * SZ_X + 4 * SZ_W);
    unsigned short* Vt  = (unsigned short*)(ws + 5 * SZ_X + 4 * SZ_W);
    unsigned short* Yb  = (unsigned short*)(ws + 6 * SZ_X + 4 * SZ_W);

    // one fused cast: 3*2^20 + 4*2^18 float4 elements = 16384 blocks
    cast_all<<<16384, 256, 0, stream>>>(query, key_, value, w_q, w_k, w_v, w_o,
                                        Xq, Xk, Xv, Wq, Wk, Wv, Wo);

    const float SCALE_Q = 0.125f * 1.4426950408889634f;  // 1/sqrt(64) * log2(e), folded into Q
    dim3 gg(HIDDEN / 128, MROWS / 128);
    gemm_bt<0><<<gg, 256, 0, stream>>>(Xq, Wq, b_q, (void*)Qb, MROWS, HIDDEN, HIDDEN, SCALE_Q);
    gemm_bt<0><<<gg, 256, 0, stream>>>(Xk, Wk, b_k, (void*)Kbf, MROWS, HIDDEN, HIDDEN, 1.0f);
    gemm_bt<1><<<gg, 256, 0, stream>>>(Xv, Wv, b_v, (void*)Vt, MROWS, HIDDEN, HIDDEN, 1.0f);

    attn_kernel<<<dim3(SS / 64, BB * HEADS), 256, 0, stream>>>(Qb, Kbf, Vt, Yb);

    gemm_bt<2><<<gg, 256, 0, stream>>>(Yb, Wo, b_o, d_out, MROWS, HIDDEN, HIDDEN, 1.0f);
}

// Round 4
// 194.847 us; speedup vs baseline: 1.8897x; 1.8163x over previous
//
#include <hip/hip_runtime.h>
#include <hip/hip_bf16.h>
#include <math.h>

#define HIDDEN 1024
#define HEADS 16
#define DK 64
#define BB 2
#define SS 2048
#define MROWS (BB*SS)  /* 4096 */

typedef __attribute__((ext_vector_type(8))) short short8;
typedef __attribute__((ext_vector_type(4))) float f32x4;
typedef __attribute__((ext_vector_type(4))) unsigned short ushort4_t;

static __device__ __forceinline__ unsigned short f2bf(float f) {
    unsigned int u = __float_as_uint(f);
    u += 0x7fffu + ((u >> 16) & 1u);
    return (unsigned short)(u >> 16);
}

// ---------------------------------------------------------------- fused cast fp32 -> bf16 (all 7 tensors)
__global__ __launch_bounds__(256) void cast_all(
    const float* __restrict__ q, const float* __restrict__ k, const float* __restrict__ v,
    const float* __restrict__ wq, const float* __restrict__ wk,
    const float* __restrict__ wv, const float* __restrict__ wo,
    unsigned short* __restrict__ Xq, unsigned short* __restrict__ Xk, unsigned short* __restrict__ Xv,
    unsigned short* __restrict__ Wq, unsigned short* __restrict__ Wk,
    unsigned short* __restrict__ Wv, unsigned short* __restrict__ Wo) {
    int i = blockIdx.x * 256 + threadIdx.x;   // float4 index
    const float* src; unsigned short* dst; int off;
    if (i < (3 << 20)) {                      // X tensors: 2^20 float4 each
        int w = i >> 20; off = i & ((1 << 20) - 1);
        src = (w == 0) ? q : (w == 1) ? k : v;
        dst = (w == 0) ? Xq : (w == 1) ? Xk : Xv;
    } else {                                  // W tensors: 2^18 float4 each
        int j = i - (3 << 20);
        int w = j >> 18; off = j & ((1 << 18) - 1);
        src = (w == 0) ? wq : (w == 1) ? wk : (w == 2) ? wv : wo;
        dst = (w == 0) ? Wq : (w == 1) ? Wk : (w == 2) ? Wv : Wo;
    }
    float4 f = reinterpret_cast<const float4*>(src)[off];
    ushort4_t o;
    o.x = f2bf(f.x); o.y = f2bf(f.y); o.z = f2bf(f.z); o.w = f2bf(f.w);
    reinterpret_cast<ushort4_t*>(dst)[off] = o;
}

// ---------------------------------------------------------------- GEMM: out = (A[M,K] * W[N,K]^T + bias) * oscale
// MODE 0: out bf16, scatter to [B,H,S,D]   (Q, K projections)
// MODE 1: out bf16, scatter to [B,H,D,S]   (V projection, pre-transposed)
// MODE 2: out fp32, [M,N] row-major        (final output projection; oscale ignored)
template<int MODE>
__global__ __launch_bounds__(256) void gemm_bt(const unsigned short* __restrict__ A,
                                               const unsigned short* __restrict__ Wt,
                                               const float* __restrict__ bias,
                                               void* __restrict__ outp,
                                               int M, int N, int K, float oscale) {
    __shared__ unsigned short As[128][40];
    __shared__ unsigned short Bs[128][40];
    const int t    = threadIdx.x;
    const int lane = t & 63;
    const int wave = t >> 6;
    const int m0 = blockIdx.y * 128;
    const int n0 = blockIdx.x * 128;
    const int row  = t >> 2;
    const int col8 = (t & 3) * 8;

    const int wm = (wave >> 1) * 64;
    const int wn = (wave & 1) * 64;
    const int lr = lane & 15;
    const int lk = (lane >> 4) * 8;

    f32x4 acc[4][4];
#pragma unroll
    for (int i = 0; i < 4; i++)
#pragma unroll
        for (int j = 0; j < 4; j++) acc[i][j] = f32x4{0.f, 0.f, 0.f, 0.f};

    for (int k0 = 0; k0 < K; k0 += 32) {
        short8 av0 = *reinterpret_cast<const short8*>(A  + (size_t)(m0 + row)      * K + k0 + col8);
        short8 av1 = *reinterpret_cast<const short8*>(A  + (size_t)(m0 + row + 64) * K + k0 + col8);
        short8 bv0 = *reinterpret_cast<const short8*>(Wt + (size_t)(n0 + row)      * K + k0 + col8);
        short8 bv1 = *reinterpret_cast<const short8*>(Wt + (size_t)(n0 + row + 64) * K + k0 + col8);
        __syncthreads();
        *reinterpret_cast<short8*>(&As[row][col8])      = av0;
        *reinterpret_cast<short8*>(&As[row + 64][col8]) = av1;
        *reinterpret_cast<short8*>(&Bs[row][col8])      = bv0;
        *reinterpret_cast<short8*>(&Bs[row + 64][col8]) = bv1;
        __syncthreads();
        short8 af[4], bfr[4];
#pragma unroll
        for (int i = 0; i < 4; i++) af[i]  = *reinterpret_cast<const short8*>(&As[wm + i * 16 + lr][lk]);
#pragma unroll
        for (int j = 0; j < 4; j++) bfr[j] = *reinterpret_cast<const short8*>(&Bs[wn + j * 16 + lr][lk]);
#pragma unroll
        for (int i = 0; i < 4; i++)
#pragma unroll
            for (int j = 0; j < 4; j++)
                acc[i][j] = __builtin_amdgcn_mfma_f32_16x16x32_bf16(af[i], bfr[j], acc[i][j], 0, 0, 0);
    }

#pragma unroll
    for (int i = 0; i < 4; i++) {
        int mrow = m0 + wm + i * 16 + (lane >> 4) * 4;
#pragma unroll
        for (int j = 0; j < 4; j++) {
            int ncol = n0 + wn + j * 16 + lr;
            float bv = bias[ncol];
            if (MODE == 2) {
                float* O = (float*)outp;
#pragma unroll
                for (int r = 0; r < 4; r++)
                    O[(size_t)(mrow + r) * N + ncol] = acc[i][j][r] + bv;
            } else {
                unsigned short* O = (unsigned short*)outp;
                int b_ = mrow >> 11;
                int h_ = ncol >> 6;
                int d_ = ncol & 63;
                if (MODE == 0) {
#pragma unroll
                    for (int r = 0; r < 4; r++) {
                        int s_ = (mrow + r) & 2047;
                        O[(((size_t)(b_ * HEADS + h_)) * SS + s_) * DK + d_] = f2bf((acc[i][j][r] + bv) * oscale);
                    }
                } else {
                    int s0 = mrow & 2047;
                    ushort4_t pk;
                    pk.x = f2bf((acc[i][j][0] + bv) * oscale);
                    pk.y = f2bf((acc[i][j][1] + bv) * oscale);
                    pk.z = f2bf((acc[i][j][2] + bv) * oscale);
                    pk.w = f2bf((acc[i][j][3] + bv) * oscale);
                    *reinterpret_cast<ushort4_t*>(O + (((size_t)(b_ * HEADS + h_) * DK + d_) * SS + s0)) = pk;
                }
            }
        }
    }
}

// ---------------------------------------------------------------- flash attention v4
// = v3 with the P-path type hazard fixed: Psh stores via ushort4_t (element-compatible
// TBAA with the short8 reads; uint2 stores in v3 let the compiler reorder P-writes vs
// pf-reads) + sched_barrier(0) fence between P-writes and pf-reads.
// LDS-shared K/V (double-buffered, global_load_lds w/ pre-swizzled source),
// 4 waves/block, 32 q/wave (128 q/block), KVBLK=64, swapped-operand MFMA.
// Q:[B,H,S,D] bf16 PRE-SCALED by 0.125*log2e; K:[B,H,S,D]; Vt:[B,H,D,S]; Y:[B,S,HIDDEN] bf16.
// LDS K tile [kv=64][d-chunks 8x16B], V tile [d=64][kv-chunks 8x16B]; both XOR-swizzled
// (chunk ^= row&7): source address pre-swizzled, ds_read applies same XOR (rule #21).
__global__ __launch_bounds__(256, 2) void attn_kernel(const unsigned short* __restrict__ Qb,
                                                      const unsigned short* __restrict__ Kb,
                                                      const unsigned short* __restrict__ Vt,
                                                      unsigned short* __restrict__ Yb) {
    __shared__ __attribute__((aligned(16))) unsigned short Ksh[2][64 * 64];
    __shared__ __attribute__((aligned(16))) unsigned short Vsh[2][64 * 64];
    __shared__ __attribute__((aligned(16))) unsigned short Psh[4][32][80];   // per-wave P, 160B row stride

    const int t    = threadIdx.x;
    const int lane = t & 63;
    const int wave = t >> 6;
    const int bh = blockIdx.y;
    const int b_ = bh >> 4, h_ = bh & 15;
    const int qbase = blockIdx.x * 128 + wave * 32;
    const unsigned short* Qp = Qb + (size_t)bh * SS * DK;
    const unsigned short* Kp = Kb + (size_t)bh * SS * DK;
    const unsigned short* Vp = Vt + (size_t)bh * DK * SS;
    const int lr = lane & 15;
    const int g  = lane >> 4;

    // staging mapping: lane i writes LDS row (base + i>>3), chunk (i&7);
    // source chunk pre-swizzled so that swizzled ds_read returns linear data.
    const int sr = lane >> 3;                 // 0..7 row-within-8
    const int cs = (lane & 7) ^ sr;           // source 16B chunk

    // Q B-frags (q cols qbase+qh*16+lr, d halves)
    short8 bq[2][2];
#pragma unroll
    for (int qh = 0; qh < 2; qh++)
#pragma unroll
        for (int dh = 0; dh < 2; dh++)
            bq[qh][dh] = *reinterpret_cast<const short8*>(
                Qp + (size_t)(qbase + qh * 16 + lr) * DK + dh * 32 + g * 8);

    f32x4 accd[4][2];
#pragma unroll
    for (int dt = 0; dt < 4; dt++)
#pragma unroll
        for (int qh = 0; qh < 2; qh++) accd[dt][qh] = f32x4{0.f, 0.f, 0.f, 0.f};
    float mi[2] = {-INFINITY, -INFINITY};
    float li[2] = {0.f, 0.f};

#define STAGE(BUF, KV0) do {                                                                 \
    __builtin_amdgcn_global_load_lds(                                                        \
        (const __attribute__((address_space(1))) unsigned int*)(Kp + (size_t)((KV0) + wave * 16 + sr) * DK + cs * 8), \
        (__attribute__((address_space(3))) unsigned int*)&Ksh[BUF][(wave * 16) * 64], 16, 0, 0); \
    __builtin_amdgcn_global_load_lds(                                                        \
        (const __attribute__((address_space(1))) unsigned int*)(Kp + (size_t)((KV0) + wave * 16 + 8 + sr) * DK + cs * 8), \
        (__attribute__((address_space(3))) unsigned int*)&Ksh[BUF][(wave * 16 + 8) * 64], 16, 0, 0); \
    __builtin_amdgcn_global_load_lds(                                                        \
        (const __attribute__((address_space(1))) unsigned int*)(Vp + (size_t)(wave * 16 + sr) * SS + (KV0) + cs * 8), \
        (__attribute__((address_space(3))) unsigned int*)&Vsh[BUF][(wave * 16) * 64], 16, 0, 0); \
    __builtin_amdgcn_global_load_lds(                                                        \
        (const __attribute__((address_space(1))) unsigned int*)(Vp + (size_t)(wave * 16 + 8 + sr) * SS + (KV0) + cs * 8), \
        (__attribute__((address_space(3))) unsigned int*)&Vsh[BUF][(wave * 16 + 8) * 64], 16, 0, 0); \
} while (0)

    STAGE(0, 0);
    __syncthreads();

    for (int kv0 = 0; kv0 < SS; kv0 += 64) {
        const int cur = (kv0 >> 6) & 1;
        if (kv0 + 64 < SS) STAGE(cur ^ 1, kv0 + 64);

        // K frags: row kv = tt*16+lr, d-chunk (h*4+g) XOR-swizzled by row
        short8 kf[4][2];
#pragma unroll
        for (int tt = 0; tt < 4; tt++)
#pragma unroll
            for (int h = 0; h < 2; h++)
                kf[tt][h] = *reinterpret_cast<const short8*>(
                    &Ksh[cur][(tt * 16 + lr) * 64 + (((h * 4 + g) ^ (lr & 7)) << 3)]);

        // QK^T -> S^T[kv][q]: lane holds kv = tt*16 + 4g + r for q-col = qh*16+lr
        f32x4 sv[2][4];
#pragma unroll
        for (int qh = 0; qh < 2; qh++)
#pragma unroll
            for (int tt = 0; tt < 4; tt++) {
                f32x4 z = f32x4{0.f, 0.f, 0.f, 0.f};
                z = __builtin_amdgcn_mfma_f32_16x16x32_bf16(kf[tt][0], bq[qh][0], z, 0, 0, 0);
                z = __builtin_amdgcn_mfma_f32_16x16x32_bf16(kf[tt][1], bq[qh][1], z, 0, 0, 0);
                sv[qh][tt] = z;
            }

        // online softmax (exp2 domain) per q-half
#pragma unroll
        for (int qh = 0; qh < 2; qh++) {
            float vmax = sv[qh][0][0];
#pragma unroll
            for (int tt = 0; tt < 4; tt++)
#pragma unroll
                for (int r = 0; r < 4; r++) vmax = fmaxf(vmax, sv[qh][tt][r]);
            vmax = fmaxf(vmax, __shfl_xor(vmax, 16));
            vmax = fmaxf(vmax, __shfl_xor(vmax, 32));
            if (!__all(vmax <= mi[qh] + 8.0f)) {
                float mnew = fmaxf(mi[qh], vmax);
                float sc = __builtin_amdgcn_exp2f(mi[qh] - mnew);
                li[qh] *= sc;
#pragma unroll
                for (int dt = 0; dt < 4; dt++)
#pragma unroll
                    for (int r = 0; r < 4; r++) accd[dt][qh][r] *= sc;
                mi[qh] = mnew;
            }
            float p[16];
            float rs = 0.f;
#pragma unroll
            for (int tt = 0; tt < 4; tt++)
#pragma unroll
                for (int r = 0; r < 4; r++) {
                    p[tt * 4 + r] = __builtin_amdgcn_exp2f(sv[qh][tt][r] - mi[qh]);
                    rs += p[tt * 4 + r];
                }
            rs += __shfl_xor(rs, 16);
            rs += __shfl_xor(rs, 32);
            li[qh] += rs;
            // pack P[kv][q]: row q local, col kv = 16*tt + 4g + r  (ushort4_t store:
            // element-type-compatible with the short8 pf read -- do NOT use uint2 here)
#pragma unroll
            for (int tt = 0; tt < 4; tt++) {
                ushort4_t pk;
                pk.x = f2bf(p[tt * 4 + 0]);
                pk.y = f2bf(p[tt * 4 + 1]);
                pk.z = f2bf(p[tt * 4 + 2]);
                pk.w = f2bf(p[tt * 4 + 3]);
                *reinterpret_cast<ushort4_t*>(&Psh[wave][qh * 16 + lr][tt * 16 + g * 4]) = pk;
            }
        }

        // fence: P-writes above must not be reordered against pf reads below
        __builtin_amdgcn_sched_barrier(0);

        // P B-frags: lane (g,lr) reads kv chunk g (+4 for second half) of row q
        short8 pf[2][2];
#pragma unroll
        for (int qh = 0; qh < 2; qh++)
#pragma unroll
            for (int h = 0; h < 2; h++)
                pf[qh][h] = *reinterpret_cast<const short8*>(
                    &Psh[wave][qh * 16 + lr][h * 32 + g * 8]);

        // PV: accd[dt][qh] += V^T[d][kv] * P[kv][q]
#pragma unroll
        for (int dt = 0; dt < 4; dt++) {
            short8 vf0 = *reinterpret_cast<const short8*>(
                &Vsh[cur][(dt * 16 + lr) * 64 + ((g ^ (lr & 7)) << 3)]);
            short8 vf1 = *reinterpret_cast<const short8*>(
                &Vsh[cur][(dt * 16 + lr) * 64 + (((4 + g) ^ (lr & 7)) << 3)]);
#pragma unroll
            for (int qh = 0; qh < 2; qh++) {
                accd[dt][qh] = __builtin_amdgcn_mfma_f32_16x16x32_bf16(vf0, pf[qh][0], accd[dt][qh], 0, 0, 0);
                accd[dt][qh] = __builtin_amdgcn_mfma_f32_16x16x32_bf16(vf1, pf[qh][1], accd[dt][qh], 0, 0, 0);
            }
        }
        __syncthreads();
    }
#undef STAGE

    float inv[2] = {1.0f / li[0], 1.0f / li[1]};
#pragma unroll
    for (int qh = 0; qh < 2; qh++) {
        size_t ob = ((size_t)b_ * SS + qbase + qh * 16 + lr) * HIDDEN + h_ * 64 + g * 4;
#pragma unroll
        for (int dt = 0; dt < 4; dt++) {
            ushort4_t o;
            o.x = f2bf(accd[dt][qh][0] * inv[qh]);
            o.y = f2bf(accd[dt][qh][1] * inv[qh]);
            o.z = f2bf(accd[dt][qh][2] * inv[qh]);
            o.w = f2bf(accd[dt][qh][3] * inv[qh]);
            *reinterpret_cast<ushort4_t*>(Yb + ob + dt * 16) = o;
        }
    }
}

// ---------------------------------------------------------------- launch
extern "C" void kernel_launch(void* const* d_in, const int* in_sizes, int n_in,
                              void* d_out, int out_size, void* d_ws, size_t ws_size,
                              hipStream_t stream) {
    const float* query = (const float*)d_in[0];
    const float* key_  = (const float*)d_in[1];
    const float* value = (const float*)d_in[2];
    const float* w_q = (const float*)d_in[3];
    const float* b_q = (const float*)d_in[4];
    const float* w_k = (const float*)d_in[5];
    const float* b_k = (const float*)d_in[6];
    const float* w_v = (const float*)d_in[7];
    const float* b_v = (const float*)d_in[8];
    const float* w_o = (const float*)d_in[9];
    const float* b_o = (const float*)d_in[10];

    const size_t SZ_X = (size_t)MROWS * HIDDEN * 2;
    const size_t SZ_W = (size_t)HIDDEN * HIDDEN * 2;
    char* ws = (char*)d_ws;
    unsigned short* Xq = (unsigned short*)(ws);
    unsigned short* Xk = (unsigned short*)(ws + SZ_X);
    unsigned short* Xv = (unsigned short*)(ws + 2 * SZ_X);
    unsigned short* Wq = (unsigned short*)(ws + 3 * SZ_X);
    unsigned short* Wk = (unsigned short*)(ws + 3 * SZ_X + SZ_W);
    unsigned short* Wv = (unsigned short*)(ws + 3 * SZ_X + 2 * SZ_W);
    unsigned short* Wo = (unsigned short*)(ws + 3 * SZ_X + 3 * SZ_W);
    unsigned short* Qb = (unsigned short*)(ws + 3 * SZ_X + 4 * SZ_W);
    unsigned short* Kbf = (unsigned short*)(ws + 4 * SZ_X + 4 * SZ_W);
    unsigned short* Vt  = (unsigned short*)(ws + 5 * SZ_X + 4 * SZ_W);
    unsigned short* Yb  = (unsigned short*)(ws + 6 * SZ_X + 4 * SZ_W);

    cast_all<<<16384, 256, 0, stream>>>(query, key_, value, w_q, w_k, w_v, w_o,
                                        Xq, Xk, Xv, Wq, Wk, Wv, Wo);

    const float SCALE_Q = 0.125f * 1.4426950408889634f;  // 1/sqrt(64) * log2(e), folded into Q
    dim3 gg(HIDDEN / 128, MROWS / 128);
    gemm_bt<0><<<gg, 256, 0, stream>>>(Xq, Wq, b_q, (void*)Qb, MROWS, HIDDEN, HIDDEN, SCALE_Q);
    gemm_bt<0><<<gg, 256, 0, stream>>>(Xk, Wk, b_k, (void*)Kbf, MROWS, HIDDEN, HIDDEN, 1.0f);
    gemm_bt<1><<<gg, 256, 0, stream>>>(Xv, Wv, b_v, (void*)Vt, MROWS, HIDDEN, HIDDEN, 1.0f);

    attn_kernel<<<dim3(SS / 128, BB * HEADS), 256, 0, stream>>>(Qb, Kbf, Vt, Yb);

    gemm_bt<2><<<gg, 256, 0, stream>>>(Yb, Wo, b_o, d_out, MROWS, HIDDEN, HIDDEN, 1.0f);
}

// Round 5
// 147.994 us; speedup vs baseline: 2.4880x; 1.3166x over previous
//
#include <hip/hip_runtime.h>
#include <hip/hip_bf16.h>
#include <math.h>

#define HIDDEN 1024
#define HEADS 16
#define DK 64
#define BB 2
#define SS 2048
#define MROWS (BB*SS)  /* 4096 */

typedef __attribute__((ext_vector_type(8))) short short8;
typedef __attribute__((ext_vector_type(4))) float f32x4;
typedef __attribute__((ext_vector_type(4))) unsigned short ushort4_t;

static __device__ __forceinline__ unsigned short f2bf(float f) {
    unsigned int u = __float_as_uint(f);
    u += 0x7fffu + ((u >> 16) & 1u);
    return (unsigned short)(u >> 16);
}

// ---------------------------------------------------------------- fused cast fp32 -> bf16 (all 7 tensors)
__global__ __launch_bounds__(256) void cast_all(
    const float* __restrict__ q, const float* __restrict__ k, const float* __restrict__ v,
    const float* __restrict__ wq, const float* __restrict__ wk,
    const float* __restrict__ wv, const float* __restrict__ wo,
    unsigned short* __restrict__ Xq, unsigned short* __restrict__ Xk, unsigned short* __restrict__ Xv,
    unsigned short* __restrict__ Wq, unsigned short* __restrict__ Wk,
    unsigned short* __restrict__ Wv, unsigned short* __restrict__ Wo) {
    int i = blockIdx.x * 256 + threadIdx.x;   // float4 index
    const float* src; unsigned short* dst; int off;
    if (i < (3 << 20)) {                      // X tensors: 2^20 float4 each
        int w = i >> 20; off = i & ((1 << 20) - 1);
        src = (w == 0) ? q : (w == 1) ? k : v;
        dst = (w == 0) ? Xq : (w == 1) ? Xk : Xv;
    } else {                                  // W tensors: 2^18 float4 each
        int j = i - (3 << 20);
        int w = j >> 18; off = j & ((1 << 18) - 1);
        src = (w == 0) ? wq : (w == 1) ? wk : (w == 2) ? wv : wo;
        dst = (w == 0) ? Wq : (w == 1) ? Wk : (w == 2) ? Wv : Wo;
    }
    float4 f = reinterpret_cast<const float4*>(src)[off];
    ushort4_t o;
    o.x = f2bf(f.x); o.y = f2bf(f.y); o.z = f2bf(f.z); o.w = f2bf(f.w);
    reinterpret_cast<ushort4_t*>(dst)[off] = o;
}

// ---------------------------------------------------------------- batched QKV projection GEMM
// grid (8, 32, 3): z=0 -> Q (scatter [B,H,S,D], scaled), z=1 -> K (same layout),
// z=2 -> V (scatter transposed [B,H,D,S]). 768 blocks = 3 blocks/CU for barrier overlap.
__global__ __launch_bounds__(256, 3) void gemm_qkv(
    const unsigned short* __restrict__ Xq, const unsigned short* __restrict__ Xk, const unsigned short* __restrict__ Xv,
    const unsigned short* __restrict__ Wq, const unsigned short* __restrict__ Wk, const unsigned short* __restrict__ Wv,
    const float* __restrict__ bq, const float* __restrict__ bk, const float* __restrict__ bv,
    unsigned short* __restrict__ Qb, unsigned short* __restrict__ Kb, unsigned short* __restrict__ Vt,
    float scale_q) {
    __shared__ unsigned short As[128][40];
    __shared__ unsigned short Bs[128][40];
    const int z = blockIdx.z;
    const unsigned short* A  = (z == 0) ? Xq : (z == 1) ? Xk : Xv;
    const unsigned short* Wt = (z == 0) ? Wq : (z == 1) ? Wk : Wv;
    const float* bias        = (z == 0) ? bq : (z == 1) ? bk : bv;
    unsigned short* O        = (z == 0) ? Qb : (z == 1) ? Kb : Vt;
    const float oscale       = (z == 0) ? scale_q : 1.0f;

    const int t    = threadIdx.x;
    const int lane = t & 63;
    const int wave = t >> 6;
    const int m0 = blockIdx.y * 128;
    const int n0 = blockIdx.x * 128;
    const int row  = t >> 2;
    const int col8 = (t & 3) * 8;

    const int wm = (wave >> 1) * 64;
    const int wn = (wave & 1) * 64;
    const int lr = lane & 15;
    const int lk = (lane >> 4) * 8;

    f32x4 acc[4][4];
#pragma unroll
    for (int i = 0; i < 4; i++)
#pragma unroll
        for (int j = 0; j < 4; j++) acc[i][j] = f32x4{0.f, 0.f, 0.f, 0.f};

    for (int k0 = 0; k0 < HIDDEN; k0 += 32) {
        short8 av0 = *reinterpret_cast<const short8*>(A  + (size_t)(m0 + row)      * HIDDEN + k0 + col8);
        short8 av1 = *reinterpret_cast<const short8*>(A  + (size_t)(m0 + row + 64) * HIDDEN + k0 + col8);
        short8 bv0 = *reinterpret_cast<const short8*>(Wt + (size_t)(n0 + row)      * HIDDEN + k0 + col8);
        short8 bv1 = *reinterpret_cast<const short8*>(Wt + (size_t)(n0 + row + 64) * HIDDEN + k0 + col8);
        __syncthreads();
        *reinterpret_cast<short8*>(&As[row][col8])      = av0;
        *reinterpret_cast<short8*>(&As[row + 64][col8]) = av1;
        *reinterpret_cast<short8*>(&Bs[row][col8])      = bv0;
        *reinterpret_cast<short8*>(&Bs[row + 64][col8]) = bv1;
        __syncthreads();
        short8 af[4], bfr[4];
#pragma unroll
        for (int i = 0; i < 4; i++) af[i]  = *reinterpret_cast<const short8*>(&As[wm + i * 16 + lr][lk]);
#pragma unroll
        for (int j = 0; j < 4; j++) bfr[j] = *reinterpret_cast<const short8*>(&Bs[wn + j * 16 + lr][lk]);
#pragma unroll
        for (int i = 0; i < 4; i++)
#pragma unroll
            for (int j = 0; j < 4; j++)
                acc[i][j] = __builtin_amdgcn_mfma_f32_16x16x32_bf16(af[i], bfr[j], acc[i][j], 0, 0, 0);
    }

#pragma unroll
    for (int i = 0; i < 4; i++) {
        int mrow = m0 + wm + i * 16 + (lane >> 4) * 4;
#pragma unroll
        for (int j = 0; j < 4; j++) {
            int ncol = n0 + wn + j * 16 + lr;
            float bv = bias[ncol];
            int b_ = mrow >> 11;
            int h_ = ncol >> 6;
            int d_ = ncol & 63;
            if (z != 2) {   // Q/K: [B,H,S,D]
#pragma unroll
                for (int r = 0; r < 4; r++) {
                    int s_ = (mrow + r) & 2047;
                    O[(((size_t)(b_ * HEADS + h_)) * SS + s_) * DK + d_] = f2bf((acc[i][j][r] + bv) * oscale);
                }
            } else {        // V: [B,H,D,S] pre-transposed; 4 regs consecutive s -> 8B store
                int s0 = mrow & 2047;
                ushort4_t pk;
                pk.x = f2bf(acc[i][j][0] + bv);
                pk.y = f2bf(acc[i][j][1] + bv);
                pk.z = f2bf(acc[i][j][2] + bv);
                pk.w = f2bf(acc[i][j][3] + bv);
                *reinterpret_cast<ushort4_t*>(O + (((size_t)(b_ * HEADS + h_) * DK + d_) * SS + s0)) = pk;
            }
        }
    }
}

// ---------------------------------------------------------------- final O-projection GEMM, 128x64 tile
// out fp32 [M,N] row-major. grid (16, 32) = 512 blocks = 2 blocks/CU.
__global__ __launch_bounds__(256) void gemm_o(const unsigned short* __restrict__ A,
                                              const unsigned short* __restrict__ Wt,
                                              const float* __restrict__ bias,
                                              float* __restrict__ O) {
    __shared__ unsigned short As[128][40];
    __shared__ unsigned short Bs[64][40];
    const int t    = threadIdx.x;
    const int lane = t & 63;
    const int wave = t >> 6;
    const int m0 = blockIdx.y * 128;
    const int n0 = blockIdx.x * 64;
    const int row  = t >> 2;        // 0..63
    const int col8 = (t & 3) * 8;

    const int wm = wave * 32;       // 4 waves stacked on M; each wave 32x64 output
    const int lr = lane & 15;
    const int lk = (lane >> 4) * 8;

    f32x4 acc[2][4];
#pragma unroll
    for (int i = 0; i < 2; i++)
#pragma unroll
        for (int j = 0; j < 4; j++) acc[i][j] = f32x4{0.f, 0.f, 0.f, 0.f};

    for (int k0 = 0; k0 < HIDDEN; k0 += 32) {
        short8 av0 = *reinterpret_cast<const short8*>(A  + (size_t)(m0 + row)      * HIDDEN + k0 + col8);
        short8 av1 = *reinterpret_cast<const short8*>(A  + (size_t)(m0 + row + 64) * HIDDEN + k0 + col8);
        short8 bv0 = *reinterpret_cast<const short8*>(Wt + (size_t)(n0 + row)      * HIDDEN + k0 + col8);
        __syncthreads();
        *reinterpret_cast<short8*>(&As[row][col8])      = av0;
        *reinterpret_cast<short8*>(&As[row + 64][col8]) = av1;
        *reinterpret_cast<short8*>(&Bs[row][col8])      = bv0;
        __syncthreads();
        short8 af[2], bfr[4];
#pragma unroll
        for (int i = 0; i < 2; i++) af[i]  = *reinterpret_cast<const short8*>(&As[wm + i * 16 + lr][lk]);
#pragma unroll
        for (int j = 0; j < 4; j++) bfr[j] = *reinterpret_cast<const short8*>(&Bs[j * 16 + lr][lk]);
#pragma unroll
        for (int i = 0; i < 2; i++)
#pragma unroll
            for (int j = 0; j < 4; j++)
                acc[i][j] = __builtin_amdgcn_mfma_f32_16x16x32_bf16(af[i], bfr[j], acc[i][j], 0, 0, 0);
    }

#pragma unroll
    for (int i = 0; i < 2; i++) {
        int mrow = m0 + wm + i * 16 + (lane >> 4) * 4;
#pragma unroll
        for (int j = 0; j < 4; j++) {
            int ncol = n0 + j * 16 + lr;
            float bv = bias[ncol];
#pragma unroll
            for (int r = 0; r < 4; r++)
                O[(size_t)(mrow + r) * HIDDEN + ncol] = acc[i][j][r] + bv;
        }
    }
}

// ---------------------------------------------------------------- flash attention v5
// v4 + (a) Psh unpadded [4][32][64] with 16B-chunk XOR swizzle (c ^= row&7, write AND read),
// (b) LDS 48 KB -> 3 blocks/CU via __launch_bounds__(256,3).
// LDS-shared K/V (double-buffered, global_load_lds w/ pre-swizzled source),
// 4 waves/block, 32 q/wave (128 q/block), KVBLK=64, swapped-operand MFMA.
// Q:[B,H,S,D] bf16 PRE-SCALED by 0.125*log2e; K:[B,H,S,D]; Vt:[B,H,D,S]; Y:[B,S,HIDDEN] bf16.
__global__ __launch_bounds__(256, 3) void attn_kernel(const unsigned short* __restrict__ Qb,
                                                      const unsigned short* __restrict__ Kb,
                                                      const unsigned short* __restrict__ Vt,
                                                      unsigned short* __restrict__ Yb) {
    __shared__ __attribute__((aligned(16))) unsigned short Ksh[2][64 * 64];
    __shared__ __attribute__((aligned(16))) unsigned short Vsh[2][64 * 64];
    __shared__ __attribute__((aligned(16))) unsigned short Psh[4][32][64];   // per-wave P, XOR-swizzled

    const int t    = threadIdx.x;
    const int lane = t & 63;
    const int wave = t >> 6;
    const int bh = blockIdx.y;
    const int b_ = bh >> 4, h_ = bh & 15;
    const int qbase = blockIdx.x * 128 + wave * 32;
    const unsigned short* Qp = Qb + (size_t)bh * SS * DK;
    const unsigned short* Kp = Kb + (size_t)bh * SS * DK;
    const unsigned short* Vp = Vt + (size_t)bh * DK * SS;
    const int lr = lane & 15;
    const int g  = lane >> 4;

    // staging mapping: lane i writes LDS row (base + i>>3), chunk (i&7);
    // source chunk pre-swizzled so that swizzled ds_read returns linear data.
    const int sr = lane >> 3;                 // 0..7 row-within-8
    const int cs = (lane & 7) ^ sr;           // source 16B chunk

    // Q B-frags (q cols qbase+qh*16+lr, d halves)
    short8 bq[2][2];
#pragma unroll
    for (int qh = 0; qh < 2; qh++)
#pragma unroll
        for (int dh = 0; dh < 2; dh++)
            bq[qh][dh] = *reinterpret_cast<const short8*>(
                Qp + (size_t)(qbase + qh * 16 + lr) * DK + dh * 32 + g * 8);

    f32x4 accd[4][2];
#pragma unroll
    for (int dt = 0; dt < 4; dt++)
#pragma unroll
        for (int qh = 0; qh < 2; qh++) accd[dt][qh] = f32x4{0.f, 0.f, 0.f, 0.f};
    float mi[2] = {-INFINITY, -INFINITY};
    float li[2] = {0.f, 0.f};

#define STAGE(BUF, KV0) do {                                                                 \
    __builtin_amdgcn_global_load_lds(                                                        \
        (const __attribute__((address_space(1))) unsigned int*)(Kp + (size_t)((KV0) + wave * 16 + sr) * DK + cs * 8), \
        (__attribute__((address_space(3))) unsigned int*)&Ksh[BUF][(wave * 16) * 64], 16, 0, 0); \
    __builtin_amdgcn_global_load_lds(                                                        \
        (const __attribute__((address_space(1))) unsigned int*)(Kp + (size_t)((KV0) + wave * 16 + 8 + sr) * DK + cs * 8), \
        (__attribute__((address_space(3))) unsigned int*)&Ksh[BUF][(wave * 16 + 8) * 64], 16, 0, 0); \
    __builtin_amdgcn_global_load_lds(                                                        \
        (const __attribute__((address_space(1))) unsigned int*)(Vp + (size_t)(wave * 16 + sr) * SS + (KV0) + cs * 8), \
        (__attribute__((address_space(3))) unsigned int*)&Vsh[BUF][(wave * 16) * 64], 16, 0, 0); \
    __builtin_amdgcn_global_load_lds(                                                        \
        (const __attribute__((address_space(1))) unsigned int*)(Vp + (size_t)(wave * 16 + 8 + sr) * SS + (KV0) + cs * 8), \
        (__attribute__((address_space(3))) unsigned int*)&Vsh[BUF][(wave * 16 + 8) * 64], 16, 0, 0); \
} while (0)

    STAGE(0, 0);
    __syncthreads();

    for (int kv0 = 0; kv0 < SS; kv0 += 64) {
        const int cur = (kv0 >> 6) & 1;
        if (kv0 + 64 < SS) STAGE(cur ^ 1, kv0 + 64);

        // K frags: row kv = tt*16+lr, d-chunk (h*4+g) XOR-swizzled by row
        short8 kf[4][2];
#pragma unroll
        for (int tt = 0; tt < 4; tt++)
#pragma unroll
            for (int h = 0; h < 2; h++)
                kf[tt][h] = *reinterpret_cast<const short8*>(
                    &Ksh[cur][(tt * 16 + lr) * 64 + (((h * 4 + g) ^ (lr & 7)) << 3)]);

        // QK^T -> S^T[kv][q]: lane holds kv = tt*16 + 4g + r for q-col = qh*16+lr
        f32x4 sv[2][4];
#pragma unroll
        for (int qh = 0; qh < 2; qh++)
#pragma unroll
            for (int tt = 0; tt < 4; tt++) {
                f32x4 z = f32x4{0.f, 0.f, 0.f, 0.f};
                z = __builtin_amdgcn_mfma_f32_16x16x32_bf16(kf[tt][0], bq[qh][0], z, 0, 0, 0);
                z = __builtin_amdgcn_mfma_f32_16x16x32_bf16(kf[tt][1], bq[qh][1], z, 0, 0, 0);
                sv[qh][tt] = z;
            }

        // online softmax (exp2 domain) per q-half
#pragma unroll
        for (int qh = 0; qh < 2; qh++) {
            float vmax = sv[qh][0][0];
#pragma unroll
            for (int tt = 0; tt < 4; tt++)
#pragma unroll
                for (int r = 0; r < 4; r++) vmax = fmaxf(vmax, sv[qh][tt][r]);
            vmax = fmaxf(vmax, __shfl_xor(vmax, 16));
            vmax = fmaxf(vmax, __shfl_xor(vmax, 32));
            if (!__all(vmax <= mi[qh] + 8.0f)) {
                float mnew = fmaxf(mi[qh], vmax);
                float sc = __builtin_amdgcn_exp2f(mi[qh] - mnew);
                li[qh] *= sc;
#pragma unroll
                for (int dt = 0; dt < 4; dt++)
#pragma unroll
                    for (int r = 0; r < 4; r++) accd[dt][qh][r] *= sc;
                mi[qh] = mnew;
            }
            float p[16];
            float rs = 0.f;
#pragma unroll
            for (int tt = 0; tt < 4; tt++)
#pragma unroll
                for (int r = 0; r < 4; r++) {
                    p[tt * 4 + r] = __builtin_amdgcn_exp2f(sv[qh][tt][r] - mi[qh]);
                    rs += p[tt * 4 + r];
                }
            rs += __shfl_xor(rs, 16);
            rs += __shfl_xor(rs, 32);
            li[qh] += rs;
            // pack P[kv][q]: row q local, kv byte 32tt+8g -> 16B chunk (2tt+(g>>1)) ^ (row&7),
            // 8B half g&1. ushort4_t store (element-compatible TBAA with short8 reads).
#pragma unroll
            for (int tt = 0; tt < 4; tt++) {
                ushort4_t pk;
                pk.x = f2bf(p[tt * 4 + 0]);
                pk.y = f2bf(p[tt * 4 + 1]);
                pk.z = f2bf(p[tt * 4 + 2]);
                pk.w = f2bf(p[tt * 4 + 3]);
                int cw = (2 * tt + (g >> 1)) ^ (lr & 7);
                *reinterpret_cast<ushort4_t*>(&Psh[wave][qh * 16 + lr][cw * 8 + (g & 1) * 4]) = pk;
            }
        }

        // fence: P-writes above must not be reordered against pf reads below
        __builtin_amdgcn_sched_barrier(0);

        // P B-frags: unswizzled chunk h*4+g of row q, same XOR
        short8 pf[2][2];
#pragma unroll
        for (int qh = 0; qh < 2; qh++)
#pragma unroll
            for (int h = 0; h < 2; h++)
                pf[qh][h] = *reinterpret_cast<const short8*>(
                    &Psh[wave][qh * 16 + lr][((h * 4 + g) ^ (lr & 7)) * 8]);

        // PV: accd[dt][qh] += V^T[d][kv] * P[kv][q]
#pragma unroll
        for (int dt = 0; dt < 4; dt++) {
            short8 vf0 = *reinterpret_cast<const short8*>(
                &Vsh[cur][(dt * 16 + lr) * 64 + ((g ^ (lr & 7)) << 3)]);
            short8 vf1 = *reinterpret_cast<const short8*>(
                &Vsh[cur][(dt * 16 + lr) * 64 + (((4 + g) ^ (lr & 7)) << 3)]);
#pragma unroll
            for (int qh = 0; qh < 2; qh++) {
                accd[dt][qh] = __builtin_amdgcn_mfma_f32_16x16x32_bf16(vf0, pf[qh][0], accd[dt][qh], 0, 0, 0);
                accd[dt][qh] = __builtin_amdgcn_mfma_f32_16x16x32_bf16(vf1, pf[qh][1], accd[dt][qh], 0, 0, 0);
            }
        }
        __syncthreads();
    }
#undef STAGE

    float inv[2] = {1.0f / li[0], 1.0f / li[1]};
#pragma unroll
    for (int qh = 0; qh < 2; qh++) {
        size_t ob = ((size_t)b_ * SS + qbase + qh * 16 + lr) * HIDDEN + h_ * 64 + g * 4;
#pragma unroll
        for (int dt = 0; dt < 4; dt++) {
            ushort4_t o;
            o.x = f2bf(accd[dt][qh][0] * inv[qh]);
            o.y = f2bf(accd[dt][qh][1] * inv[qh]);
            o.z = f2bf(accd[dt][qh][2] * inv[qh]);
            o.w = f2bf(accd[dt][qh][3] * inv[qh]);
            *reinterpret_cast<ushort4_t*>(Yb + ob + dt * 16) = o;
        }
    }
}

// ---------------------------------------------------------------- launch
extern "C" void kernel_launch(void* const* d_in, const int* in_sizes, int n_in,
                              void* d_out, int out_size, void* d_ws, size_t ws_size,
                              hipStream_t stream) {
    const float* query = (const float*)d_in[0];
    const float* key_  = (const float*)d_in[1];
    const float* value = (const float*)d_in[2];
    const float* w_q = (const float*)d_in[3];
    const float* b_q = (const float*)d_in[4];
    const float* w_k = (const float*)d_in[5];
    const float* b_k = (const float*)d_in[6];
    const float* w_v = (const float*)d_in[7];
    const float* b_v = (const float*)d_in[8];
    const float* w_o = (const float*)d_in[9];
    const float* b_o = (const float*)d_in[10];

    const size_t SZ_X = (size_t)MROWS * HIDDEN * 2;
    const size_t SZ_W = (size_t)HIDDEN * HIDDEN * 2;
    char* ws = (char*)d_ws;
    unsigned short* Xq = (unsigned short*)(ws);
    unsigned short* Xk = (unsigned short*)(ws + SZ_X);
    unsigned short* Xv = (unsigned short*)(ws + 2 * SZ_X);
    unsigned short* Wq = (unsigned short*)(ws + 3 * SZ_X);
    unsigned short* Wk = (unsigned short*)(ws + 3 * SZ_X + SZ_W);
    unsigned short* Wv = (unsigned short*)(ws + 3 * SZ_X + 2 * SZ_W);
    unsigned short* Wo = (unsigned short*)(ws + 3 * SZ_X + 3 * SZ_W);
    unsigned short* Qb = (unsigned short*)(ws + 3 * SZ_X + 4 * SZ_W);
    unsigned short* Kbf = (unsigned short*)(ws + 4 * SZ_X + 4 * SZ_W);
    unsigned short* Vt  = (unsigned short*)(ws + 5 * SZ_X + 4 * SZ_W);
    unsigned short* Yb  = (unsigned short*)(ws + 6 * SZ_X + 4 * SZ_W);

    cast_all<<<16384, 256, 0, stream>>>(query, key_, value, w_q, w_k, w_v, w_o,
                                        Xq, Xk, Xv, Wq, Wk, Wv, Wo);

    const float SCALE_Q = 0.125f * 1.4426950408889634f;  // 1/sqrt(64) * log2(e), folded into Q
    gemm_qkv<<<dim3(HIDDEN / 128, MROWS / 128, 3), 256, 0, stream>>>(
        Xq, Xk, Xv, Wq, Wk, Wv, b_q, b_k, b_v, Qb, Kbf, Vt, SCALE_Q);

    attn_kernel<<<dim3(SS / 128, BB * HEADS), 256, 0, stream>>>(Qb, Kbf, Vt, Yb);

    gemm_o<<<dim3(HIDDEN / 64, MROWS / 128), 256, 0, stream>>>(Yb, Wo, b_o, (float*)d_out);
}